// Round 1
// baseline (224.004 us; speedup 1.0000x reference)
//
#include <hip/hip_runtime.h>

// Fully-fused LSTM-heads + 4-layer MLP, fp32, one thread = RPT rows.
// Weights staged in LDS (padded rows, float4-readable, transposed where
// consumed column-wise). All activation arrays in registers with fully
// unrolled loops (compile-time indices only).

#define KSEQ 11
#define HH   2
#define CIN  34
#define CMID 51
#define POUT 5
#define BLK  256
#define RPT  2

#define CIN_P  36   // 34 padded to multiple of 4 (16B-aligned rows)
#define CMID_P 52   // 51 padded

typedef float f32x2 __attribute__((ext_vector_type(2)));

__device__ __forceinline__ f32x2 splat2(float v) { f32x2 r; r.x = v; r.y = v; return r; }

__device__ __forceinline__ float fast_exp(float x) {
#if __has_builtin(__builtin_amdgcn_exp2f)
    return __builtin_amdgcn_exp2f(x * 1.44269504088896340736f);
#else
    return __expf(x);
#endif
}
__device__ __forceinline__ float fast_rcp(float x) {
#if __has_builtin(__builtin_amdgcn_rcpf)
    return __builtin_amdgcn_rcpf(x);
#else
    return 1.0f / x;
#endif
}
__device__ __forceinline__ float sigmoid1(float x) {
    return fast_rcp(1.0f + fast_exp(-x));
}
__device__ __forceinline__ float tanh1(float x) {
    float e = fast_exp(2.0f * x);            // exp(2x)
    return 1.0f - 2.0f * fast_rcp(e + 1.0f); // (e-1)/(e+1)
}

__global__ __launch_bounds__(BLK, 2)
void fused_rnn_mlp(const float* __restrict__ input,
                   const float* __restrict__ W_ih, const float* __restrict__ b_ih,
                   const float* __restrict__ b_hh,
                   const float* __restrict__ W1, const float* __restrict__ b1,
                   const float* __restrict__ W2, const float* __restrict__ b2,
                   const float* __restrict__ W3, const float* __restrict__ b3,
                   const float* __restrict__ W4, const float* __restrict__ b4,
                   float* __restrict__ out, int nrows)
{
    __shared__ __align__(16) float sWih[KSEQ * 16];      // [k][g][h]
    __shared__ __align__(16) float sBg [KSEQ * 8];       // b_ih + b_hh
    __shared__ __align__(16) float sW1 [CMID * CIN_P];   // [n1][k], natural
    __shared__ __align__(16) float sW2t[CMID * CMID_P];  // [n1][j] = W2[j][n1] (transposed)
    __shared__ __align__(16) float sW3t[CMID * CIN_P];   // [n2][m] = W3[m][n2] (transposed)
    __shared__ __align__(16) float sW4 [POUT * CIN_P];   // [p][m], natural
    __shared__ float sB1[CMID];
    __shared__ float sB2[CMID];
    __shared__ float sB3[CIN];
    __shared__ float sB4[POUT];

    const int tid = threadIdx.x;

    // ---- cooperative weight staging (coalesced-ish, once per block) ----
    for (int i = tid; i < KSEQ * 16; i += BLK) sWih[i] = W_ih[i];
    for (int i = tid; i < KSEQ * 8;  i += BLK) sBg[i]  = b_ih[i] + b_hh[i];
    for (int i = tid; i < CMID * CIN_P; i += BLK) {
        int n = i / CIN_P, k = i - n * CIN_P;
        sW1[i] = (k < CIN) ? W1[n * CIN + k] : 0.0f;
    }
    for (int i = tid; i < CMID * CMID_P; i += BLK) {
        int n = i / CMID_P, j = i - n * CMID_P;
        sW2t[i] = (j < CMID) ? W2[j * CMID + n] : 0.0f;
    }
    for (int i = tid; i < CMID * CIN_P; i += BLK) {
        int n = i / CIN_P, m = i - n * CIN_P;
        sW3t[i] = (m < CIN) ? W3[m * CMID + n] : 0.0f;
    }
    for (int i = tid; i < POUT * CIN_P; i += BLK) {
        int p = i / CIN_P, m = i - p * CIN_P;
        sW4[i] = (m < CIN) ? W4[p * CIN + m] : 0.0f;
    }
    for (int i = tid; i < CMID; i += BLK) { sB1[i] = b1[i]; sB2[i] = b2[i]; }
    for (int i = tid; i < CIN;  i += BLK) sB3[i] = b3[i];
    for (int i = tid; i < POUT; i += BLK) sB4[i] = b4[i];
    __syncthreads();

    const long long row0 = ((long long)blockIdx.x * BLK + tid) * RPT;
    if (row0 + RPT > nrows) return;

    // ---- load two rows (rows are 8B-aligned: 34*4 = 136) ----
    f32x2 xin[CIN];
    {
        const float2* p0 = reinterpret_cast<const float2*>(input + row0 * CIN);
        const float2* p1 = reinterpret_cast<const float2*>(input + (row0 + 1) * CIN);
        #pragma unroll
        for (int j = 0; j < CIN / 2; ++j) {
            float2 a = p0[j], b = p1[j];
            xin[2 * j    ].x = a.x; xin[2 * j    ].y = b.x;
            xin[2 * j + 1].x = a.y; xin[2 * j + 1].y = b.y;
        }
    }

    // ---- LSTM heads -> cat[0..21], passthrough -> cat[22..33], pad zeros ----
    f32x2 cat[CIN_P];
    #pragma unroll
    for (int j = 2 * KSEQ; j < CIN; ++j) cat[j] = xin[j];
    cat[CIN]     = splat2(0.0f);
    cat[CIN + 1] = splat2(0.0f);

    #pragma unroll
    for (int k = 0; k < KSEQ; ++k) {
        f32x2 x0 = xin[2 * k], x1 = xin[2 * k + 1];
        #pragma unroll
        for (int j = 0; j < HH; ++j) {
            // gates: i = g[0:2], f = g[2:4] (unused), g = g[4:6], o = g[6:8]
            f32x2 gi = splat2(sBg[k * 8 + j])     + x0 * splat2(sWih[k * 16 + 2 * j])
                                                  + x1 * splat2(sWih[k * 16 + 2 * j + 1]);
            f32x2 gg = splat2(sBg[k * 8 + 4 + j]) + x0 * splat2(sWih[k * 16 + 8 + 2 * j])
                                                  + x1 * splat2(sWih[k * 16 + 9 + 2 * j]);
            f32x2 go = splat2(sBg[k * 8 + 6 + j]) + x0 * splat2(sWih[k * 16 + 12 + 2 * j])
                                                  + x1 * splat2(sWih[k * 16 + 13 + 2 * j]);
            f32x2 c, h;
            c.x = sigmoid1(gi.x) * tanh1(gg.x);
            c.y = sigmoid1(gi.y) * tanh1(gg.y);
            h.x = sigmoid1(go.x) * tanh1(c.x);
            h.y = sigmoid1(go.y) * tanh1(c.y);
            cat[2 * k + j] = h;
        }
    }

    // ---- L1 fused into L2 accumulate: z2[j] = b2[j] + sum_n relu(L1_n) * W2[j][n] ----
    f32x2 z2[CMID_P];
    #pragma unroll
    for (int j = 0; j < CMID; ++j) z2[j] = splat2(sB2[j]);
    z2[CMID] = splat2(0.0f);

    #pragma unroll
    for (int n = 0; n < CMID; ++n) {
        f32x2 a = splat2(sB1[n]);
        const float4* wp = reinterpret_cast<const float4*>(&sW1[n * CIN_P]);
        #pragma unroll
        for (int q = 0; q < CIN_P / 4; ++q) {
            float4 w = wp[q];
            a += cat[4 * q]     * splat2(w.x) + cat[4 * q + 1] * splat2(w.y)
               + cat[4 * q + 2] * splat2(w.z) + cat[4 * q + 3] * splat2(w.w);
        }
        f32x2 t;
        t.x = fmaxf(a.x, 0.0f); t.y = fmaxf(a.y, 0.0f);
        const float4* w2 = reinterpret_cast<const float4*>(&sW2t[n * CMID_P]);
        #pragma unroll
        for (int q = 0; q < CMID_P / 4; ++q) {
            float4 w = w2[q];
            z2[4 * q]     += t * splat2(w.x);
            z2[4 * q + 1] += t * splat2(w.y);
            z2[4 * q + 2] += t * splat2(w.z);
            z2[4 * q + 3] += t * splat2(w.w);
        }
    }

    // ---- L2 relu fused into L3 accumulate: z3[m] = b3[m] + sum_n relu(z2[n]) * W3[m][n] ----
    f32x2 z3[CIN_P];
    #pragma unroll
    for (int m = 0; m < CIN; ++m) z3[m] = splat2(sB3[m]);
    z3[CIN]     = splat2(0.0f);
    z3[CIN + 1] = splat2(0.0f);

    #pragma unroll
    for (int n = 0; n < CMID; ++n) {
        f32x2 t;
        t.x = fmaxf(z2[n].x, 0.0f); t.y = fmaxf(z2[n].y, 0.0f);
        const float4* w3 = reinterpret_cast<const float4*>(&sW3t[n * CIN_P]);
        #pragma unroll
        for (int q = 0; q < CIN_P / 4; ++q) {
            float4 w = w3[q];
            z3[4 * q]     += t * splat2(w.x);
            z3[4 * q + 1] += t * splat2(w.y);
            z3[4 * q + 2] += t * splat2(w.z);
            z3[4 * q + 3] += t * splat2(w.w);
        }
    }
    #pragma unroll
    for (int m = 0; m < CIN; ++m) {
        z3[m].x = fmaxf(z3[m].x, 0.0f);
        z3[m].y = fmaxf(z3[m].y, 0.0f);
    }

    // ---- L4 + sigmoid ----
    float o0[POUT], o1[POUT];
    #pragma unroll
    for (int p = 0; p < POUT; ++p) {
        f32x2 a = splat2(sB4[p]);
        const float4* w4 = reinterpret_cast<const float4*>(&sW4[p * CIN_P]);
        #pragma unroll
        for (int q = 0; q < CIN_P / 4; ++q) {
            float4 w = w4[q];
            a += z3[4 * q]     * splat2(w.x) + z3[4 * q + 1] * splat2(w.y)
               + z3[4 * q + 2] * splat2(w.z) + z3[4 * q + 3] * splat2(w.w);
        }
        o0[p] = sigmoid1(a.x);
        o1[p] = sigmoid1(a.y);
    }

    float* op0 = out + row0 * POUT;
    #pragma unroll
    for (int p = 0; p < POUT; ++p) op0[p] = o0[p];
    float* op1 = out + (row0 + 1) * POUT;
    #pragma unroll
    for (int p = 0; p < POUT; ++p) op1[p] = o1[p];
}

extern "C" void kernel_launch(void* const* d_in, const int* in_sizes, int n_in,
                              void* d_out, int out_size, void* d_ws, size_t ws_size,
                              hipStream_t stream)
{
    const float* input = (const float*)d_in[0];
    const float* W_ih  = (const float*)d_in[1];
    const float* b_ih  = (const float*)d_in[2];
    const float* b_hh  = (const float*)d_in[3];
    const float* W1    = (const float*)d_in[4];
    const float* b1    = (const float*)d_in[5];
    const float* W2    = (const float*)d_in[6];
    const float* b2    = (const float*)d_in[7];
    const float* W3    = (const float*)d_in[8];
    const float* b3    = (const float*)d_in[9];
    const float* W4    = (const float*)d_in[10];
    const float* b4    = (const float*)d_in[11];
    float* out = (float*)d_out;

    int nrows = in_sizes[0] / CIN;
    int grid  = (nrows + BLK * RPT - 1) / (BLK * RPT);
    hipLaunchKernelGGL(fused_rnn_mlp, dim3(grid), dim3(BLK), 0, stream,
                       input, W_ih, b_ih, b_hh, W1, b1, W2, b2, W3, b3, W4, b4,
                       out, nrows);
}

// Round 3
// 147.961 us; speedup vs baseline: 1.5139x; 1.5139x over previous
//
#include <hip/hip_runtime.h>

// Fused LSTM-heads + 4-layer MLP using v_dot2_f32_f16 (full-rate f16 dot,
// fp32 accumulate). Weights converted to half2 pairs in LDS once per block,
// biases folded in as an extra K-element (activation padded with 1.0).
// One thread = 2 rows; all activations in registers, fully unrolled.

#define KSEQ 11
#define CIN  34
#define CMID 51
#define POUT 5
#define BLK  256
#define RPT  2

#define P1    18   // input pairs for L1/L4: 17 data pairs + {., 1.0}
#define P1PAD 20   // padded to multiple of 4 (b128-readable)
#define P2    26   // input pairs for L2/L3: 25 data pairs + {z[50], 1.0}
#define P2PAD 28

typedef _Float16 h2 __attribute__((ext_vector_type(2)));

__device__ __forceinline__ h2 pk(float a, float b) {
    auto r = __builtin_amdgcn_cvt_pkrtz(a, b);     // __fp16 ext_vector(2)
    union { decltype(r) f; h2 h; } c; c.f = r; return c.h;
}
__device__ __forceinline__ h2 as_h2(unsigned u) {
    union { unsigned u; h2 h; } c; c.u = u; return c.h;
}
__device__ __forceinline__ unsigned as_u32(h2 h) {
    union { h2 h; unsigned u; } c; c.h = h; return c.u;
}
__device__ __forceinline__ float fdot2f(h2 a, h2 b, float c) {
#if __has_builtin(__builtin_amdgcn_fdot2)
    return __builtin_amdgcn_fdot2(a, b, c, false);
#else
    return (float)a.x * (float)b.x + (float)a.y * (float)b.y + c;
#endif
}

__device__ __forceinline__ float fast_exp(float x) {
#if __has_builtin(__builtin_amdgcn_exp2f)
    return __builtin_amdgcn_exp2f(x * 1.44269504088896340736f);
#else
    return __expf(x);
#endif
}
__device__ __forceinline__ float fast_rcp(float x) {
#if __has_builtin(__builtin_amdgcn_rcpf)
    return __builtin_amdgcn_rcpf(x);
#else
    return 1.0f / x;
#endif
}
__device__ __forceinline__ float sig1(float x)  { return fast_rcp(1.0f + fast_exp(-x)); }
__device__ __forceinline__ float tanh1(float x) {
    float e = fast_exp(2.0f * x);
    return 1.0f - 2.0f * fast_rcp(e + 1.0f);
}

// Dot of two activation-pair arrays (2 rows) against one weight row in LDS.
// NP = pairs actually used; NW4 = uint4 reads per row (NPAD/4).
template<int NP, int NW4>
__device__ __forceinline__ void dot2x(const unsigned* __restrict__ wrow,
                                      const h2* a, const h2* b,
                                      float& r0, float& r1)
{
    const uint4* w4 = reinterpret_cast<const uint4*>(wrow);
    float s0 = 0.0f, s1 = 0.0f;
    #pragma unroll
    for (int q = 0; q < NW4; ++q) {
        uint4 w = w4[q];
        if (4 * q + 0 < NP) { h2 h = as_h2(w.x); s0 = fdot2f(a[4*q+0], h, s0); s1 = fdot2f(b[4*q+0], h, s1); }
        if (4 * q + 1 < NP) { h2 h = as_h2(w.y); s0 = fdot2f(a[4*q+1], h, s0); s1 = fdot2f(b[4*q+1], h, s1); }
        if (4 * q + 2 < NP) { h2 h = as_h2(w.z); s0 = fdot2f(a[4*q+2], h, s0); s1 = fdot2f(b[4*q+2], h, s1); }
        if (4 * q + 3 < NP) { h2 h = as_h2(w.w); s0 = fdot2f(a[4*q+3], h, s0); s1 = fdot2f(b[4*q+3], h, s1); }
    }
    r0 = s0; r1 = s1;
}

__global__ __launch_bounds__(BLK, 4)
void fused_rnn_mlp(const float* __restrict__ input,
                   const float* __restrict__ W_ih, const float* __restrict__ b_ih,
                   const float* __restrict__ b_hh,
                   const float* __restrict__ W1, const float* __restrict__ b1,
                   const float* __restrict__ W2, const float* __restrict__ b2,
                   const float* __restrict__ W3, const float* __restrict__ b3,
                   const float* __restrict__ W4, const float* __restrict__ b4,
                   float* __restrict__ out, int nrows)
{
    __shared__ __align__(16) float    sWih[KSEQ * 16];
    __shared__ __align__(16) float    sBg [KSEQ * 8];
    __shared__ __align__(16) unsigned sW1 [CMID * P1PAD];  // [n][pair(k)] + bias pair
    __shared__ __align__(16) unsigned sW2 [CMID * P2PAD];  // [j][pair(n)] + bias pair
    __shared__ __align__(16) unsigned sW3 [CIN  * P2PAD];  // [m][pair(j)] + bias pair
    __shared__ __align__(16) unsigned sW4 [POUT * P1PAD];  // [p][pair(m)] + bias pair

    const int tid = threadIdx.x;

    // ---- stage + convert weights to half2 (once per block) ----
    for (int i = tid; i < KSEQ * 16; i += BLK) sWih[i] = W_ih[i];
    for (int i = tid; i < KSEQ * 8;  i += BLK) sBg[i]  = b_ih[i] + b_hh[i];
    for (int i = tid; i < CMID * P1PAD; i += BLK) {
        int n = i / P1PAD, c = i - n * P1PAD;
        float a = 0.0f, b = 0.0f;
        if (c < 17)      { a = W1[n * CIN + 2 * c]; b = W1[n * CIN + 2 * c + 1]; }
        else if (c == 17){ a = b1[n]; }
        sW1[i] = as_u32(pk(a, b));
    }
    for (int i = tid; i < CMID * P2PAD; i += BLK) {
        int n = i / P2PAD, c = i - n * P2PAD;
        float a = 0.0f, b = 0.0f;
        if (c < 25)      { a = W2[n * CMID + 2 * c]; b = W2[n * CMID + 2 * c + 1]; }
        else if (c == 25){ a = W2[n * CMID + 50]; b = b2[n]; }
        sW2[i] = as_u32(pk(a, b));
    }
    for (int i = tid; i < CIN * P2PAD; i += BLK) {
        int m = i / P2PAD, c = i - m * P2PAD;
        float a = 0.0f, b = 0.0f;
        if (c < 25)      { a = W3[m * CMID + 2 * c]; b = W3[m * CMID + 2 * c + 1]; }
        else if (c == 25){ a = W3[m * CMID + 50]; b = b3[m]; }
        sW3[i] = as_u32(pk(a, b));
    }
    for (int i = tid; i < POUT * P1PAD; i += BLK) {
        int p = i / P1PAD, c = i - p * P1PAD;
        float a = 0.0f, b = 0.0f;
        if (c < 17)      { a = W4[p * CIN + 2 * c]; b = W4[p * CIN + 2 * c + 1]; }
        else if (c == 17){ a = b4[p]; }
        sW4[i] = as_u32(pk(a, b));
    }
    __syncthreads();

    const long long row0 = ((long long)blockIdx.x * BLK + tid) * RPT;
    if (row0 + RPT > nrows) return;

    // ---- load 2 rows as float2 (rows are 8B aligned: 34*4 = 136B) ----
    float2 xa[17], xb[17];
    {
        const float2* pa = reinterpret_cast<const float2*>(input + row0 * CIN);
        const float2* pb = reinterpret_cast<const float2*>(input + (row0 + 1) * CIN);
        #pragma unroll
        for (int j = 0; j < 17; ++j) { xa[j] = pa[j]; xb[j] = pb[j]; }
    }

    // ---- LSTM heads (fp32) -> cat pairs (f16), + passthrough, + bias-one ----
    h2 ca[P1], cb[P1];
    #pragma unroll
    for (int k = 0; k < KSEQ; ++k) {
        const float4* wk = reinterpret_cast<const float4*>(&sWih[k * 16]);
        float4 WA = wk[0];  // gates i: rows g0,g1
        float4 WC = wk[2];  // gates g: rows g4,g5
        float4 WD = wk[3];  // gates o: rows g6,g7
        const float4* bk = reinterpret_cast<const float4*>(&sBg[k * 8]);
        float4 B0 = bk[0];  // b0..b3
        float4 B1 = bk[1];  // b4..b7

        // row a
        {
            float x0 = xa[k].x, x1 = xa[k].y;
            float gi0 = B0.x + x0 * WA.x + x1 * WA.y;
            float gi1 = B0.y + x0 * WA.z + x1 * WA.w;
            float gg0 = B1.x + x0 * WC.x + x1 * WC.y;
            float gg1 = B1.y + x0 * WC.z + x1 * WC.w;
            float go0 = B1.z + x0 * WD.x + x1 * WD.y;
            float go1 = B1.w + x0 * WD.z + x1 * WD.w;
            float c0 = sig1(gi0) * tanh1(gg0);
            float c1 = sig1(gi1) * tanh1(gg1);
            float h0 = sig1(go0) * tanh1(c0);
            float h1 = sig1(go1) * tanh1(c1);
            ca[k] = pk(h0, h1);
        }
        // row b
        {
            float x0 = xb[k].x, x1 = xb[k].y;
            float gi0 = B0.x + x0 * WA.x + x1 * WA.y;
            float gi1 = B0.y + x0 * WA.z + x1 * WA.w;
            float gg0 = B1.x + x0 * WC.x + x1 * WC.y;
            float gg1 = B1.y + x0 * WC.z + x1 * WC.w;
            float go0 = B1.z + x0 * WD.x + x1 * WD.y;
            float go1 = B1.w + x0 * WD.z + x1 * WD.w;
            float c0 = sig1(gi0) * tanh1(gg0);
            float c1 = sig1(gi1) * tanh1(gg1);
            float h0 = sig1(go0) * tanh1(c0);
            float h1 = sig1(go1) * tanh1(c1);
            cb[k] = pk(h0, h1);
        }
    }
    #pragma unroll
    for (int t = 0; t < 6; ++t) {       // x[22..33] -> pairs 11..16
        ca[11 + t] = pk(xa[11 + t].x, xa[11 + t].y);
        cb[11 + t] = pk(xb[11 + t].x, xb[11 + t].y);
    }
    ca[17] = pk(1.0f, 0.0f);
    cb[17] = pk(1.0f, 0.0f);

    // ---- L1: z1[n] = relu(dot(cat, W1[n]) + b1[n]) -> f16 pairs ----
    h2 za[P2], zb[P2];
    #pragma unroll
    for (int n = 0; n < 50; n += 2) {
        float a0, a1, b0, b1v;
        dot2x<P1, P1PAD / 4>(&sW1[n * P1PAD],       ca, cb, a0, b0);
        dot2x<P1, P1PAD / 4>(&sW1[(n + 1) * P1PAD], ca, cb, a1, b1v);
        za[n / 2] = pk(fmaxf(a0, 0.0f), fmaxf(a1, 0.0f));
        zb[n / 2] = pk(fmaxf(b0, 0.0f), fmaxf(b1v, 0.0f));
    }
    {
        float a0, b0;
        dot2x<P1, P1PAD / 4>(&sW1[50 * P1PAD], ca, cb, a0, b0);
        za[25] = pk(fmaxf(a0, 0.0f), 1.0f);
        zb[25] = pk(fmaxf(b0, 0.0f), 1.0f);
    }

    // ---- L2: z2[j] = relu(dot(z1, W2[j]) + b2[j]) -> f16 pairs ----
    h2 ya[P2], yb[P2];
    #pragma unroll
    for (int j = 0; j < 50; j += 2) {
        float a0, a1, b0, b1v;
        dot2x<P2, P2PAD / 4>(&sW2[j * P2PAD],       za, zb, a0, b0);
        dot2x<P2, P2PAD / 4>(&sW2[(j + 1) * P2PAD], za, zb, a1, b1v);
        ya[j / 2] = pk(fmaxf(a0, 0.0f), fmaxf(a1, 0.0f));
        yb[j / 2] = pk(fmaxf(b0, 0.0f), fmaxf(b1v, 0.0f));
    }
    {
        float a0, b0;
        dot2x<P2, P2PAD / 4>(&sW2[50 * P2PAD], za, zb, a0, b0);
        ya[25] = pk(fmaxf(a0, 0.0f), 1.0f);
        yb[25] = pk(fmaxf(b0, 0.0f), 1.0f);
    }

    // ---- L3: z3[m] = relu(dot(z2, W3[m]) + b3[m]) -> f16 pairs ----
    h2 ta[P1], tb[P1];
    #pragma unroll
    for (int m = 0; m < CIN; m += 2) {
        float a0, a1, b0, b1v;
        dot2x<P2, P2PAD / 4>(&sW3[m * P2PAD],       ya, yb, a0, b0);
        dot2x<P2, P2PAD / 4>(&sW3[(m + 1) * P2PAD], ya, yb, a1, b1v);
        ta[m / 2] = pk(fmaxf(a0, 0.0f), fmaxf(a1, 0.0f));
        tb[m / 2] = pk(fmaxf(b0, 0.0f), fmaxf(b1v, 0.0f));
    }
    ta[17] = pk(1.0f, 0.0f);
    tb[17] = pk(1.0f, 0.0f);

    // ---- L4 + sigmoid + store ----
    float oa[POUT], ob[POUT];
    #pragma unroll
    for (int p = 0; p < POUT; ++p) {
        float a0, b0;
        dot2x<P1, P1PAD / 4>(&sW4[p * P1PAD], ta, tb, a0, b0);
        oa[p] = sig1(a0);
        ob[p] = sig1(b0);
    }
    float* op0 = out + row0 * POUT;
    float* op1 = out + (row0 + 1) * POUT;
    #pragma unroll
    for (int p = 0; p < POUT; ++p) { op0[p] = oa[p]; op1[p] = ob[p]; }
}

extern "C" void kernel_launch(void* const* d_in, const int* in_sizes, int n_in,
                              void* d_out, int out_size, void* d_ws, size_t ws_size,
                              hipStream_t stream)
{
    const float* input = (const float*)d_in[0];
    const float* W_ih  = (const float*)d_in[1];
    const float* b_ih  = (const float*)d_in[2];
    const float* b_hh  = (const float*)d_in[3];
    const float* W1    = (const float*)d_in[4];
    const float* b1    = (const float*)d_in[5];
    const float* W2    = (const float*)d_in[6];
    const float* b2    = (const float*)d_in[7];
    const float* W3    = (const float*)d_in[8];
    const float* b3    = (const float*)d_in[9];
    const float* W4    = (const float*)d_in[10];
    const float* b4    = (const float*)d_in[11];
    float* out = (float*)d_out;

    int nrows = in_sizes[0] / CIN;
    int grid  = (nrows + BLK * RPT - 1) / (BLK * RPT);
    hipLaunchKernelGGL(fused_rnn_mlp, dim3(grid), dim3(BLK), 0, stream,
                       input, W_ih, b_ih, b_hh, W1, b1, W2, b2, W3, b3, W4, b4,
                       out, nrows);
}